// Round 8
// baseline (290.767 us; speedup 1.0000x reference)
//
#include <hip/hip_runtime.h>
#include <hip/hip_bf16.h>
#include <math.h>

typedef __bf16 bf16;
typedef bf16 bf16x4 __attribute__((ext_vector_type(4)));
typedef bf16 bf16x8 __attribute__((ext_vector_type(8)));
typedef float floatx4 __attribute__((ext_vector_type(4)));
typedef float floatx16 __attribute__((ext_vector_type(16)));

#define MFMA16(a, b, c) __builtin_amdgcn_mfma_f32_16x16x32_bf16(a, b, c, 0, 0, 0)
#define MFMA32(a, b, c) __builtin_amdgcn_mfma_f32_32x32x16_bf16(a, b, c, 0, 0, 0)

__device__ __forceinline__ void split2(float v, bf16& h, bf16& l) {
    h = (bf16)v;
    l = (bf16)(v - (float)h);
}

// pack two f32 -> one u32 of 2 bf16 (lo in [15:0], hi in [31:16])
__device__ __forceinline__ unsigned cvt_pk(float lo, float hi) {
    unsigned r;
    asm("v_cvt_pk_bf16_f32 %0, %1, %2" : "=v"(r) : "v"(lo), "v"(hi));
    return r;
}

// swap a.hi_lanes <-> b.lo_lanes
__device__ __forceinline__ void pl32swap(unsigned& a, unsigned& b) {
    asm("v_permlane32_swap_b32 %0, %1" : "+v"(a), "+v"(b));
}

// async global->LDS, 16 B per lane; LDS dest = wave-uniform base + lane*16
__device__ __forceinline__ void gload16(const bf16* g, bf16* l) {
    __builtin_amdgcn_global_load_lds(
        (const __attribute__((address_space(1))) void*)g,
        (__attribute__((address_space(3))) void*)l, 16, 0, 0);
}

// ---------------------------------------------------------------------------
// K0: z<4: transpose+split fp32 weights W[k][n] -> hi/lo bf16 Wt[n][k]
//     (vectorized bf16x8 stores); z==4: split x fp32 -> hi/lo bf16 (flat)
// ---------------------------------------------------------------------------
__global__ void prep_kernel(const float* __restrict__ xf,
                            const float* __restrict__ wq, const float* __restrict__ wk,
                            const float* __restrict__ wv, const float* __restrict__ wo,
                            bf16* __restrict__ xh, bf16* __restrict__ xl,
                            bf16* __restrict__ wt_qkv_h, bf16* __restrict__ wt_qkv_l,
                            bf16* __restrict__ wt_o_h) {
    const int z = blockIdx.z;
    if (z == 4) {
        const int tid = threadIdx.y * 32 + threadIdx.x;
        const int bid = blockIdx.y * 32 + blockIdx.x;
        const size_t i = ((size_t)bid * 256 + tid) * 16;
#pragma unroll
        for (int half = 0; half < 2; half++) {
            float4 a = *(const float4*)(xf + i + half * 8);
            float4 b = *(const float4*)(xf + i + half * 8 + 4);
            bf16x8 oh, ol;
            float f[8] = {a.x, a.y, a.z, a.w, b.x, b.y, b.z, b.w};
#pragma unroll
            for (int j = 0; j < 8; j++) { bf16 h, l; split2(f[j], h, l); oh[j] = h; ol[j] = l; }
            *(bf16x8*)(xh + i + half * 8) = oh;
            *(bf16x8*)(xl + i + half * 8) = ol;
        }
        return;
    }
    const float* src = (z == 0) ? wq : (z == 1) ? wk : (z == 2) ? wv : wo;
    bf16* dsth = (z < 3) ? (wt_qkv_h + (size_t)z * 1024 * 1024) : wt_o_h;
    bf16* dstl = (z < 3) ? (wt_qkv_l + (size_t)z * 1024 * 1024) : nullptr;
    __shared__ float tile[32][33];
    const int x0 = blockIdx.x * 32, y0 = blockIdx.y * 32;
    const int tx = threadIdx.x, ty = threadIdx.y;  // (32,8)
    for (int i = 0; i < 32; i += 8)
        tile[ty + i][tx] = src[(size_t)(y0 + ty + i) * 1024 + x0 + tx];
    __syncthreads();
    // vectorized transpose-out: thread -> (out row r, col-chunk c0, half hf);
    // out[n=x0+r][k=y0+c0*8+j] = src[k][n] = tile[c0*8+j][r]
    const int id = ty * 32 + tx;
    const int r = id & 31, c0 = (id >> 5) & 3, hf = id >> 7;
    bf16x8 v;
#pragma unroll
    for (int j = 0; j < 8; j++) {
        bf16 h, l;
        split2(tile[c0 * 8 + j][r], h, l);
        v[j] = hf ? l : h;
    }
    bf16* dst = hf ? dstl : dsth;
    if (dst) *(bf16x8*)&dst[(size_t)(x0 + r) * 1024 + y0 + c0 * 8] = v;
}

// ---------------------------------------------------------------------------
// K1: FUSED QKV GEMM over N=3072 (Q,K: 3-term split-bf16; V: 1-term),
//   grid 32x24 = 768 blocks = 3 blocks/CU (launch_bounds(256,3)).
//   Q/K epilogue writes hi/lo [B,H,S,D]; K blocks also reduce
//   kn = sum_d (hi+lo)^2 in-register. V epilogue writes Vt[B,H,D,S].
// ---------------------------------------------------------------------------
__global__ __launch_bounds__(256, 3) void gemm_qkv(
    const bf16* __restrict__ Ah, const bf16* __restrict__ Al,
    const bf16* __restrict__ Bth, const bf16* __restrict__ Btl,
    const float* __restrict__ bq, const float* __restrict__ bk,
    const float* __restrict__ bv,
    bf16* __restrict__ Qh, bf16* __restrict__ Ql,
    bf16* __restrict__ Kh, bf16* __restrict__ Kl,
    bf16* __restrict__ VtG, float* __restrict__ knG) {
    __shared__ bf16 Ash[128 * 32];
    __shared__ bf16 Asl[128 * 32];
    __shared__ bf16 Bsh[128 * 32];
    __shared__ bf16 Bsl[128 * 32];

    const int t = threadIdx.x;
    const int lane = t & 63, wave = t >> 6;
    const int quad = lane >> 4, l16 = lane & 15;
    const int m0 = blockIdx.x * 128, n0 = blockIdx.y * 128;
    const int wm = (wave >> 1) * 64, wn = (wave & 1) * 64;
    const int which = n0 >> 10;  // 0=Q 1=K 2=V

    const int srow = wave * 16 + (lane >> 2);
    const int scol = (lane & 3) * 8;
    const bf16* gAh = Ah + (size_t)(m0 + srow) * 1024 + scol;
    const bf16* gAl = Al + (size_t)(m0 + srow) * 1024 + scol;
    const bf16* gBh = Bth + (size_t)(n0 + srow) * 1024 + scol;
    const bf16* gBl = Btl + (size_t)(n0 + srow) * 1024 + scol;
    bf16* lAh = &Ash[wave * 16 * 32];
    bf16* lAl = &Asl[wave * 16 * 32];
    bf16* lBh = &Bsh[wave * 16 * 32];
    bf16* lBl = &Bsl[wave * 16 * 32];

    floatx4 acc[4][4] = {};

    if (which < 2) {
        // -------- 3-term split path (Q and K) --------
        for (int k0 = 0; k0 < 1024; k0 += 32) {
            gload16(gAh + k0, lAh);
            gload16(gAh + 64 * 1024 + k0, lAh + 64 * 32);
            gload16(gBh + k0, lBh);
            gload16(gBh + 64 * 1024 + k0, lBh + 64 * 32);
            gload16(gAl + k0, lAl);
            gload16(gAl + 64 * 1024 + k0, lAl + 64 * 32);
            gload16(gBl + k0, lBl);
            gload16(gBl + 64 * 1024 + k0, lBl + 64 * 32);
            __syncthreads();
            bf16x8 afh[4], bfh[4], afl[4], bfl[4];
#pragma unroll
            for (int i = 0; i < 4; i++) {
                afh[i] = *(bf16x8*)&Ash[(wm + i * 16 + l16) * 32 + quad * 8];
                afl[i] = *(bf16x8*)&Asl[(wm + i * 16 + l16) * 32 + quad * 8];
            }
#pragma unroll
            for (int j = 0; j < 4; j++) {
                bfh[j] = *(bf16x8*)&Bsh[(wn + j * 16 + l16) * 32 + quad * 8];
                bfl[j] = *(bf16x8*)&Bsl[(wn + j * 16 + l16) * 32 + quad * 8];
            }
#pragma unroll
            for (int i = 0; i < 4; i++)
#pragma unroll
                for (int j = 0; j < 4; j++) {
                    acc[i][j] = MFMA16(afh[i], bfh[j], acc[i][j]);
                    acc[i][j] = MFMA16(afh[i], bfl[j], acc[i][j]);
                    acc[i][j] = MFMA16(afl[i], bfh[j], acc[i][j]);
                }
            __syncthreads();
        }

        const float* bias = (which == 0) ? bq : bk;
        bf16* Dh = (which == 0) ? Qh : Kh;
        bf16* Dl = (which == 0) ? Ql : Kl;
        const int hh = ((n0 + wn) & 1023) >> 6;  // head of this wave's 64 cols
#pragma unroll
        for (int i = 0; i < 4; i++) {
            float ks[4] = {0.f, 0.f, 0.f, 0.f};
#pragma unroll
            for (int j = 0; j < 4; j++) {
                const int col = n0 + wn + j * 16 + l16;
                const int o = col & 1023;
                const int h = o >> 6, d = o & 63;
                const float bvv = bias[o];
                const int gm0 = m0 + wm + i * 16 + quad * 4;
                const int b = gm0 >> 11;
#pragma unroll
                for (int r = 0; r < 4; r++) {
                    const int gm = gm0 + r;
                    const int s = gm & 2047;
                    const size_t idx = (size_t)((b * 16 + h) * 2048 + s) * 64 + d;
                    const float val = acc[i][j][r] + bvv;
                    bf16 hi, lo;
                    split2(val, hi, lo);
                    Dh[idx] = hi;
                    Dl[idx] = lo;
                    const float vr = (float)hi + (float)lo;
                    ks[r] += vr * vr;
                }
            }
            if (which == 1) {
                const int gm0 = m0 + wm + i * 16 + quad * 4;
                const int b = gm0 >> 11;
#pragma unroll
                for (int r = 0; r < 4; r++) {
                    float s = ks[r];
                    s += __shfl_xor(s, 1, 16);
                    s += __shfl_xor(s, 2, 16);
                    s += __shfl_xor(s, 4, 16);
                    s += __shfl_xor(s, 8, 16);
                    if (l16 == 0) {
                        const int gm = gm0 + r;
                        knG[(size_t)(b * 16 + hh) * 2048 + (gm & 2047)] = s;
                    }
                }
            }
        }
    } else {
        // -------- 1-term path (V) --------
        for (int k0 = 0; k0 < 1024; k0 += 32) {
            gload16(gAh + k0, lAh);
            gload16(gAh + 64 * 1024 + k0, lAh + 64 * 32);
            gload16(gBh + k0, lBh);
            gload16(gBh + 64 * 1024 + k0, lBh + 64 * 32);
            __syncthreads();
            bf16x8 af[4], bf_[4];
#pragma unroll
            for (int i = 0; i < 4; i++)
                af[i] = *(bf16x8*)&Ash[(wm + i * 16 + l16) * 32 + quad * 8];
#pragma unroll
            for (int j = 0; j < 4; j++)
                bf_[j] = *(bf16x8*)&Bsh[(wn + j * 16 + l16) * 32 + quad * 8];
#pragma unroll
            for (int i = 0; i < 4; i++)
#pragma unroll
                for (int j = 0; j < 4; j++)
                    acc[i][j] = MFMA16(af[i], bf_[j], acc[i][j]);
            __syncthreads();
        }

#pragma unroll
        for (int i = 0; i < 4; i++)
#pragma unroll
            for (int j = 0; j < 4; j++) {
                const int o = (n0 + wn + j * 16 + l16) & 1023;
                const int h = o >> 6, d = o & 63;
                const float bvv = bv[o];
                const int gm0 = m0 + wm + i * 16 + quad * 4;
                const int b = gm0 >> 11;
                bf16x4 pv;
#pragma unroll
                for (int r = 0; r < 4; r++) pv[r] = (bf16)(acc[i][j][r] + bvv);
                const int s0 = gm0 & 2047;
                *(bf16x4*)&VtG[((size_t)((b * 16 + h) * 64 + d)) * 2048 + s0] = pv;
            }
    }
}

// ---------------------------------------------------------------------------
// K2: flash attention, YAT scores, 32x32x16 MFMA, in-register P via
//   cvt_pk_bf16 + permlane32_swap, XOR-swizzled stride-64 reg staging
//   (async-split), double-buffered, constant-shift softmax. (R1-proven)
//   Per wave: 32 q rows. Lane layout: q = lane&31, h = lane>>5.
// ---------------------------------------------------------------------------
__global__ __launch_bounds__(256, 2) void attn_kernel(
    const bf16* __restrict__ Qh, const bf16* __restrict__ Ql,
    const bf16* __restrict__ Kh, const bf16* __restrict__ Kl,
    const bf16* __restrict__ VtG, const float* __restrict__ knG,
    bf16* __restrict__ O, const float* __restrict__ alphap) {
    __shared__ bf16 Ksh[2][64 * 64];
    __shared__ bf16 Ksl[2][64 * 64];
    __shared__ bf16 Vs[2][64 * 64];
    __shared__ __align__(16) float knL[2][64];

    const int t = threadIdx.x, lane = t & 63, wave = t >> 6;
    const int l31 = lane & 31, h = lane >> 5;
    const int bh = blockIdx.x;
    const int qw = blockIdx.y * 128 + wave * 32;

    const float alpha = alphap[0];
    const float C = powf(8.0f / log1pf(64.0f), alpha) * 1.44269504f;

    // Q fragments (B-operand): lane holds Q[q=l31][d = cb*16 + h*8 + j]
    const size_t qbase = ((size_t)bh * 2048 + qw + l31) * 64;
    bf16x8 bqh[4], bql[4];
#pragma unroll
    for (int cb = 0; cb < 4; cb++) {
        bqh[cb] = *(const bf16x8*)(Qh + qbase + cb * 16 + h * 8);
        bql[cb] = *(const bf16x8*)(Ql + qbase + cb * 16 + h * 8);
    }
    float qn = 0.f;
#pragma unroll
    for (int cb = 0; cb < 4; cb++)
#pragma unroll
        for (int j = 0; j < 8; j++) {
            float x = (float)bqh[cb][j] + (float)bql[cb][j];
            qn += x * x;
        }
    qn += __shfl_xor(qn, 32, 64);
    const float qne = qn + 1e-5f;

    floatx16 acco[2] = {};
    float l_run = 0.f;

    // staging map: thread t stages rows srow, srow+32; 8 elems at scol
    const int srow = t >> 3;
    const int scol = (t & 7) * 8;
    const int smask = (srow & 7) * 8;  // (srow+32)&7 == srow&7
    const int so0 = srow * 64 + (scol ^ smask);
    const int so1 = (srow + 32) * 64 + (scol ^ smask);
    const size_t vrow0 = ((size_t)bh * 64 + srow) * 2048;
    const size_t vrow1 = vrow0 + (size_t)32 * 2048;
    const float* knB = knG + (size_t)bh * 2048;

    // fragment read offsets: row-block rb (32 rows) x col-block cb (16 elems)
    const int fmask = (l31 & 7) * 8;
    int foff[2][4];
#pragma unroll
    for (int rb = 0; rb < 2; rb++)
#pragma unroll
        for (int cb = 0; cb < 4; cb++)
            foff[rb][cb] = (rb * 32 + l31) * 64 + ((cb * 16 + h * 8) ^ fmask);

    auto do_chunk = [&](int ib) {
        const bf16* KH = Ksh[ib];
        const bf16* KL = Ksl[ib];
        const bf16* VV = Vs[ib];
        const float* knC = knL[ib];

        // QK^T (swapped): D[key][q], 3-term split
        floatx16 acc[2] = {};
#pragma unroll
        for (int cb = 0; cb < 4; cb++)
#pragma unroll
            for (int kb = 0; kb < 2; kb++) {
                bf16x8 ah = *(const bf16x8*)&KH[foff[kb][cb]];
                bf16x8 al = *(const bf16x8*)&KL[foff[kb][cb]];
                acc[kb] = MFMA32(ah, bqh[cb], acc[kb]);
                acc[kb] = MFMA32(ah, bql[cb], acc[kb]);
                acc[kb] = MFMA32(al, bqh[cb], acc[kb]);
            }

        // softmax (constant shift) + pack P into PV B-operand fragments.
        // lane's key for acc[kb][r]: kb*32 + (r&3) + 8*(r>>2) + 4*h
        unsigned pw[2][8];
        float rs = 0.f;
#pragma unroll
        for (int kb = 0; kb < 2; kb++) {
            float p[16];
#pragma unroll
            for (int g2 = 0; g2 < 4; g2++) {
                const floatx4 knv = *(const floatx4*)&knC[kb * 32 + g2 * 8 + h * 4];
#pragma unroll
                for (int j = 0; j < 4; j++) {
                    const int r = g2 * 4 + j;
                    const float d = acc[kb][r];
                    const float e = fmaf(-2.0f, d, qne + knv[j]);
                    const float s = fmaf(C * d * d, __builtin_amdgcn_rcpf(e), -110.0f);
                    const float pp = __builtin_amdgcn_exp2f(s);
                    rs += pp;
                    p[r] = pp;
                }
            }
#pragma unroll
            for (int g = 0; g < 2; g++) {
                unsigned a0 = cvt_pk(p[8 * g + 0], p[8 * g + 1]);
                unsigned a1 = cvt_pk(p[8 * g + 2], p[8 * g + 3]);
                unsigned b0 = cvt_pk(p[8 * g + 4], p[8 * g + 5]);
                unsigned b1 = cvt_pk(p[8 * g + 6], p[8 * g + 7]);
                pl32swap(a0, b0);
                pl32swap(a1, b1);
                pw[kb][g * 4 + 0] = a0;
                pw[kb][g * 4 + 1] = a1;
                pw[kb][g * 4 + 2] = b0;
                pw[kb][g * 4 + 3] = b1;
            }
        }
        l_run += rs;

        // PV: D[d][q] += V[d][key] * P[key][q]
#pragma unroll
        for (int db = 0; db < 2; db++)
#pragma unroll
            for (int g4 = 0; g4 < 4; g4++) {
                bf16x8 vf = *(const bf16x8*)&VV[foff[db][g4]];
                union { unsigned u[4]; bf16x8 v; } pu;
                pu.u[0] = pw[g4 >> 1][(g4 & 1) * 4 + 0];
                pu.u[1] = pw[g4 >> 1][(g4 & 1) * 4 + 1];
                pu.u[2] = pw[g4 >> 1][(g4 & 1) * 4 + 2];
                pu.u[3] = pw[g4 >> 1][(g4 & 1) * 4 + 3];
                acco[db] = MFMA32(vf, pu.v, acco[db]);
            }
    };

    {
        const size_t kb0 = (size_t)(bh * 2048) * 64;
        bf16x8 k0 = *(const bf16x8*)(Kh + kb0 + srow * 64 + scol);
        bf16x8 k1 = *(const bf16x8*)(Kh + kb0 + (32 + srow) * 64 + scol);
        bf16x8 c0 = *(const bf16x8*)(Kl + kb0 + srow * 64 + scol);
        bf16x8 c1 = *(const bf16x8*)(Kl + kb0 + (32 + srow) * 64 + scol);
        bf16x8 v0 = *(const bf16x8*)(VtG + vrow0 + scol);
        bf16x8 v1 = *(const bf16x8*)(VtG + vrow1 + scol);
        *(bf16x8*)&Ksh[0][so0] = k0;
        *(bf16x8*)&Ksh[0][so1] = k1;
        *(bf16x8*)&Ksl[0][so0] = c0;
        *(bf16x8*)&Ksl[0][so1] = c1;
        *(bf16x8*)&Vs[0][so0] = v0;
        *(bf16x8*)&Vs[0][so1] = v1;
        if (t < 16) *(float4*)&knL[0][t * 4] = *(const float4*)(knB + t * 4);
    }
    __syncthreads();

    for (int ic = 0; ic < 31; ic++) {
        const int cur = ic & 1, nxt = cur ^ 1;
        const int kc = (ic + 1) * 64;
        const size_t kbg = (size_t)(bh * 2048 + kc) * 64;
        bf16x8 nk0 = *(const bf16x8*)(Kh + kbg + srow * 64 + scol);
        bf16x8 nk1 = *(const bf16x8*)(Kh + kbg + (32 + srow) * 64 + scol);
        bf16x8 nc0 = *(const bf16x8*)(Kl + kbg + srow * 64 + scol);
        bf16x8 nc1 = *(const bf16x8*)(Kl + kbg + (32 + srow) * 64 + scol);
        bf16x8 nv0 = *(const bf16x8*)(VtG + vrow0 + kc + scol);
        bf16x8 nv1 = *(const bf16x8*)(VtG + vrow1 + kc + scol);
        float4 nkn;
        if (t < 16) nkn = *(const float4*)(knB + kc + t * 4);

        do_chunk(cur);

        *(bf16x8*)&Ksh[nxt][so0] = nk0;
        *(bf16x8*)&Ksh[nxt][so1] = nk1;
        *(bf16x8*)&Ksl[nxt][so0] = nc0;
        *(bf16x8*)&Ksl[nxt][so1] = nc1;
        *(bf16x8*)&Vs[nxt][so0] = nv0;
        *(bf16x8*)&Vs[nxt][so1] = nv1;
        if (t < 16) *(float4*)&knL[nxt][t * 4] = nkn;
        __syncthreads();
    }
    do_chunk(1);

    const float l_tot = l_run + __shfl_xor(l_run, 32, 64);
    const float rl = 1.0f / l_tot;
    const int b = bh >> 4, hh = bh & 15;
    const int q = qw + l31;
    const size_t obase = (size_t)(b * 2048 + q) * 1024 + hh * 64;
#pragma unroll
    for (int db = 0; db < 2; db++)
#pragma unroll
        for (int g2 = 0; g2 < 4; g2++) {
            bf16x4 ov;
#pragma unroll
            for (int j = 0; j < 4; j++) ov[j] = (bf16)(acco[db][g2 * 4 + j] * rl);
            const int d = db * 32 + g2 * 8 + h * 4;
            *(bf16x4*)&O[obase + d] = ov;
        }
}

// ---------------------------------------------------------------------------
// K3: out-proj GEMM, K-SPLIT x2 (blockIdx.z, K=512 each) -> 1024 blocks =
//   4 blocks/CU; fp32 atomicAdd into memset-zeroed output; bias on kz==0.
// ---------------------------------------------------------------------------
__global__ __launch_bounds__(256, 4) void gemm_out(
    const bf16* __restrict__ A, const bf16* __restrict__ Bt,
    const float* __restrict__ bias, float* __restrict__ outC) {
    __shared__ bf16 As[128 * 32];
    __shared__ bf16 Bs[64 * 32];

    const int t = threadIdx.x;
    const int lane = t & 63, wave = t >> 6;
    const int quad = lane >> 4, l16 = lane & 15;
    const int m0 = blockIdx.x * 128, n0 = blockIdx.y * 64;
    const int kz = blockIdx.z;
    const int wm = (wave >> 1) * 64, wn = (wave & 1) * 32;

    const int srow = wave * 16 + (lane >> 2);
    const int scol = (lane & 3) * 8;
    const bf16* gA0 = A + (size_t)(m0 + srow) * 1024 + scol + kz * 512;
    const bf16* gB0 = Bt + (size_t)(n0 + srow) * 1024 + scol + kz * 512;
    bf16* lA = &As[wave * 16 * 32];
    bf16* lB = &Bs[wave * 16 * 32];

    floatx4 acc[4][2] = {};

    for (int k0 = 0; k0 < 512; k0 += 32) {
        gload16(gA0 + k0, lA);
        gload16(gA0 + 64 * 1024 + k0, lA + 64 * 32);
        gload16(gB0 + k0, lB);
        __syncthreads();
        bf16x8 af[4], bf_[2];
#pragma unroll
        for (int i = 0; i < 4; i++)
            af[i] = *(bf16x8*)&As[(wm + i * 16 + l16) * 32 + quad * 8];
#pragma unroll
        for (int j = 0; j < 2; j++)
            bf_[j] = *(bf16x8*)&Bs[(wn + j * 16 + l16) * 32 + quad * 8];
#pragma unroll
        for (int i = 0; i < 4; i++)
#pragma unroll
            for (int j = 0; j < 2; j++)
                acc[i][j] = MFMA16(af[i], bf_[j], acc[i][j]);
        __syncthreads();
    }

#pragma unroll
    for (int i = 0; i < 4; i++)
#pragma unroll
        for (int j = 0; j < 2; j++) {
            const int col = n0 + wn + j * 16 + l16;
            const float bvv = (kz == 0) ? bias[col] : 0.f;
#pragma unroll
            for (int r = 0; r < 4; r++) {
                const int gm = m0 + wm + i * 16 + quad * 4 + r;
                atomicAdd(&outC[(size_t)gm * 1024 + col], acc[i][j][r] + bvv);
            }
        }
}

// ---------------------------------------------------------------------------
extern "C" void kernel_launch(void* const* d_in, const int* in_sizes, int n_in,
                              void* d_out, int out_size, void* d_ws, size_t ws_size,
                              hipStream_t stream) {
    const float* x  = (const float*)d_in[0];
    const float* wq = (const float*)d_in[1];
    const float* bq = (const float*)d_in[2];
    const float* wk = (const float*)d_in[3];
    const float* bk = (const float*)d_in[4];
    const float* wv = (const float*)d_in[5];
    const float* bv = (const float*)d_in[6];
    const float* wo = (const float*)d_in[7];
    const float* bo = (const float*)d_in[8];
    const float* alpha = (const float*)d_in[9];

    char* ws = (char*)d_ws;
    const size_t MB = 1024 * 1024;
    bf16* wqkv_h = (bf16*)(ws);              // 6 MB
    bf16* wqkv_l = (bf16*)(ws + 6 * MB);     // 6 MB
    bf16* wo_h   = (bf16*)(ws + 12 * MB);    // 2 MB
    float* knG   = (float*)(ws + 14 * MB);   // 0.25 MB
    bf16* x_h    = (bf16*)(ws + 16 * MB);    // 8 MB
    bf16* x_l    = (bf16*)(ws + 24 * MB);    // 8 MB
    bf16* Q_h    = (bf16*)(ws + 32 * MB);    // 8 MB
    bf16* Q_l    = (bf16*)(ws + 40 * MB);    // 8 MB
    bf16* K_h    = (bf16*)(ws + 48 * MB);    // 8 MB
    bf16* K_l    = (bf16*)(ws + 56 * MB);    // 8 MB
    bf16* Vt_g   = (bf16*)(ws + 64 * MB);    // 8 MB, [B,H,D,S]
    bf16* Ob     = (bf16*)(ws);              // aliases wqkv (dead after QKV GEMM)

    hipMemsetAsync(d_out, 0, (size_t)4096 * 1024 * sizeof(float), stream);
    prep_kernel<<<dim3(32, 32, 5), dim3(32, 8), 0, stream>>>(
        x, wq, wk, wv, wo, x_h, x_l, wqkv_h, wqkv_l, wo_h);
    gemm_qkv<<<dim3(32, 24), 256, 0, stream>>>(
        x_h, x_l, wqkv_h, wqkv_l, bq, bk, bv, Q_h, Q_l, K_h, K_l, Vt_g, knG);
    attn_kernel<<<dim3(32, 16), 256, 0, stream>>>(
        Q_h, Q_l, K_h, K_l, Vt_g, knG, Ob, alpha);
    gemm_out<<<dim3(32, 16, 2), 256, 0, stream>>>(Ob, wo_h, bo, (float*)d_out);
}

// Round 9
// 264.136 us; speedup vs baseline: 1.1008x; 1.1008x over previous
//
#include <hip/hip_runtime.h>
#include <hip/hip_bf16.h>
#include <math.h>

typedef __bf16 bf16;
typedef bf16 bf16x4 __attribute__((ext_vector_type(4)));
typedef bf16 bf16x8 __attribute__((ext_vector_type(8)));
typedef float floatx4 __attribute__((ext_vector_type(4)));
typedef float floatx16 __attribute__((ext_vector_type(16)));

#define MFMA16(a, b, c) __builtin_amdgcn_mfma_f32_16x16x32_bf16(a, b, c, 0, 0, 0)
#define MFMA32(a, b, c) __builtin_amdgcn_mfma_f32_32x32x16_bf16(a, b, c, 0, 0, 0)

__device__ __forceinline__ void split2(float v, bf16& h, bf16& l) {
    h = (bf16)v;
    l = (bf16)(v - (float)h);
}

// pack two f32 -> one u32 of 2 bf16 (lo in [15:0], hi in [31:16])
__device__ __forceinline__ unsigned cvt_pk(float lo, float hi) {
    unsigned r;
    asm("v_cvt_pk_bf16_f32 %0, %1, %2" : "=v"(r) : "v"(lo), "v"(hi));
    return r;
}

// swap a.hi_lanes <-> b.lo_lanes
__device__ __forceinline__ void pl32swap(unsigned& a, unsigned& b) {
    asm("v_permlane32_swap_b32 %0, %1" : "+v"(a), "+v"(b));
}

// async global->LDS, 16 B per lane; LDS dest = wave-uniform base + lane*16
__device__ __forceinline__ void gload16(const bf16* g, bf16* l) {
    __builtin_amdgcn_global_load_lds(
        (const __attribute__((address_space(1))) void*)g,
        (__attribute__((address_space(3))) void*)l, 16, 0, 0);
}

// ---------------------------------------------------------------------------
// K0: z<4: transpose+split fp32 weights W[k][n] -> hi/lo bf16 Wt[n][k]
//     (bf16x8 stores, coalescing-correct lane map); z==4: split x (flat)
// ---------------------------------------------------------------------------
__global__ void prep_kernel(const float* __restrict__ xf,
                            const float* __restrict__ wq, const float* __restrict__ wk,
                            const float* __restrict__ wv, const float* __restrict__ wo,
                            bf16* __restrict__ xh, bf16* __restrict__ xl,
                            bf16* __restrict__ wt_qkv_h, bf16* __restrict__ wt_qkv_l,
                            bf16* __restrict__ wt_o_h) {
    const int z = blockIdx.z;
    if (z == 4) {
        const int tid = threadIdx.y * 32 + threadIdx.x;
        const int bid = blockIdx.y * 32 + blockIdx.x;
        const size_t i = ((size_t)bid * 256 + tid) * 16;
#pragma unroll
        for (int half = 0; half < 2; half++) {
            float4 a = *(const float4*)(xf + i + half * 8);
            float4 b = *(const float4*)(xf + i + half * 8 + 4);
            bf16x8 oh, ol;
            float f[8] = {a.x, a.y, a.z, a.w, b.x, b.y, b.z, b.w};
#pragma unroll
            for (int j = 0; j < 8; j++) { bf16 h, l; split2(f[j], h, l); oh[j] = h; ol[j] = l; }
            *(bf16x8*)(xh + i + half * 8) = oh;
            *(bf16x8*)(xl + i + half * 8) = ol;
        }
        return;
    }
    const float* src = (z == 0) ? wq : (z == 1) ? wk : (z == 2) ? wv : wo;
    bf16* dsth = (z < 3) ? (wt_qkv_h + (size_t)z * 1024 * 1024) : wt_o_h;
    bf16* dstl = (z < 3) ? (wt_qkv_l + (size_t)z * 1024 * 1024) : nullptr;
    __shared__ float tile[32][33];
    const int x0 = blockIdx.x * 32, y0 = blockIdx.y * 32;
    const int tx = threadIdx.x, ty = threadIdx.y;  // (32,8)
    for (int i = 0; i < 32; i += 8)
        tile[ty + i][tx] = src[(size_t)(y0 + ty + i) * 1024 + x0 + tx];
    __syncthreads();
    // vectorized transpose-out: Wt[n=x0+r][k=y0+c0*8+j] = tile[c0*8+j][r].
    // lane map: r=id>>3, hf=(id>>2)&1, c0=id&3 -> lanes 0-3 write 64 B of
    // row r (hi), lanes 4-7 same row (lo): coalesced 64-B segments; LDS
    // reads hit 32 distinct banks (hf pair = same-address broadcast).
    const int id = ty * 32 + tx;
    const int r = id >> 3, hf = (id >> 2) & 1, c0 = id & 3;
    bf16x8 v;
#pragma unroll
    for (int j = 0; j < 8; j++) {
        bf16 h, l;
        split2(tile[c0 * 8 + j][r], h, l);
        v[j] = hf ? l : h;
    }
    bf16* dst = hf ? dstl : dsth;
    if (dst) *(bf16x8*)&dst[(size_t)(x0 + r) * 1024 + y0 + c0 * 8] = v;
}

// ---------------------------------------------------------------------------
// K1: FUSED QKV GEMM over N=3072 (Q,K: 3-term split-bf16; V: 1-term),
//   grid 32x24 = 768 blocks = 3 blocks/CU (launch_bounds(256,3)).
//   Q/K epilogue writes hi/lo [B,H,S,D]; K blocks also reduce
//   kn = sum_d (hi+lo)^2 in-register. V epilogue writes Vt[B,H,D,S].
// ---------------------------------------------------------------------------
__global__ __launch_bounds__(256, 3) void gemm_qkv(
    const bf16* __restrict__ Ah, const bf16* __restrict__ Al,
    const bf16* __restrict__ Bth, const bf16* __restrict__ Btl,
    const float* __restrict__ bq, const float* __restrict__ bk,
    const float* __restrict__ bv,
    bf16* __restrict__ Qh, bf16* __restrict__ Ql,
    bf16* __restrict__ Kh, bf16* __restrict__ Kl,
    bf16* __restrict__ VtG, float* __restrict__ knG) {
    __shared__ bf16 Ash[128 * 32];
    __shared__ bf16 Asl[128 * 32];
    __shared__ bf16 Bsh[128 * 32];
    __shared__ bf16 Bsl[128 * 32];

    const int t = threadIdx.x;
    const int lane = t & 63, wave = t >> 6;
    const int quad = lane >> 4, l16 = lane & 15;
    const int m0 = blockIdx.x * 128, n0 = blockIdx.y * 128;
    const int wm = (wave >> 1) * 64, wn = (wave & 1) * 64;
    const int which = n0 >> 10;  // 0=Q 1=K 2=V

    const int srow = wave * 16 + (lane >> 2);
    const int scol = (lane & 3) * 8;
    const bf16* gAh = Ah + (size_t)(m0 + srow) * 1024 + scol;
    const bf16* gAl = Al + (size_t)(m0 + srow) * 1024 + scol;
    const bf16* gBh = Bth + (size_t)(n0 + srow) * 1024 + scol;
    const bf16* gBl = Btl + (size_t)(n0 + srow) * 1024 + scol;
    bf16* lAh = &Ash[wave * 16 * 32];
    bf16* lAl = &Asl[wave * 16 * 32];
    bf16* lBh = &Bsh[wave * 16 * 32];
    bf16* lBl = &Bsl[wave * 16 * 32];

    floatx4 acc[4][4] = {};

    if (which < 2) {
        // -------- 3-term split path (Q and K) --------
        for (int k0 = 0; k0 < 1024; k0 += 32) {
            gload16(gAh + k0, lAh);
            gload16(gAh + 64 * 1024 + k0, lAh + 64 * 32);
            gload16(gBh + k0, lBh);
            gload16(gBh + 64 * 1024 + k0, lBh + 64 * 32);
            gload16(gAl + k0, lAl);
            gload16(gAl + 64 * 1024 + k0, lAl + 64 * 32);
            gload16(gBl + k0, lBl);
            gload16(gBl + 64 * 1024 + k0, lBl + 64 * 32);
            __syncthreads();
            bf16x8 afh[4], bfh[4], afl[4], bfl[4];
#pragma unroll
            for (int i = 0; i < 4; i++) {
                afh[i] = *(bf16x8*)&Ash[(wm + i * 16 + l16) * 32 + quad * 8];
                afl[i] = *(bf16x8*)&Asl[(wm + i * 16 + l16) * 32 + quad * 8];
            }
#pragma unroll
            for (int j = 0; j < 4; j++) {
                bfh[j] = *(bf16x8*)&Bsh[(wn + j * 16 + l16) * 32 + quad * 8];
                bfl[j] = *(bf16x8*)&Bsl[(wn + j * 16 + l16) * 32 + quad * 8];
            }
#pragma unroll
            for (int i = 0; i < 4; i++)
#pragma unroll
                for (int j = 0; j < 4; j++) {
                    acc[i][j] = MFMA16(afh[i], bfh[j], acc[i][j]);
                    acc[i][j] = MFMA16(afh[i], bfl[j], acc[i][j]);
                    acc[i][j] = MFMA16(afl[i], bfh[j], acc[i][j]);
                }
            __syncthreads();
        }

        const float* bias = (which == 0) ? bq : bk;
        bf16* Dh = (which == 0) ? Qh : Kh;
        bf16* Dl = (which == 0) ? Ql : Kl;
        const int hh = ((n0 + wn) & 1023) >> 6;  // head of this wave's 64 cols
#pragma unroll
        for (int i = 0; i < 4; i++) {
            float ks[4] = {0.f, 0.f, 0.f, 0.f};
#pragma unroll
            for (int j = 0; j < 4; j++) {
                const int col = n0 + wn + j * 16 + l16;
                const int o = col & 1023;
                const int h = o >> 6, d = o & 63;
                const float bvv = bias[o];
                const int gm0 = m0 + wm + i * 16 + quad * 4;
                const int b = gm0 >> 11;
#pragma unroll
                for (int r = 0; r < 4; r++) {
                    const int gm = gm0 + r;
                    const int s = gm & 2047;
                    const size_t idx = (size_t)((b * 16 + h) * 2048 + s) * 64 + d;
                    const float val = acc[i][j][r] + bvv;
                    bf16 hi, lo;
                    split2(val, hi, lo);
                    Dh[idx] = hi;
                    Dl[idx] = lo;
                    const float vr = (float)hi + (float)lo;
                    ks[r] += vr * vr;
                }
            }
            if (which == 1) {
                const int gm0 = m0 + wm + i * 16 + quad * 4;
                const int b = gm0 >> 11;
#pragma unroll
                for (int r = 0; r < 4; r++) {
                    float s = ks[r];
                    s += __shfl_xor(s, 1, 16);
                    s += __shfl_xor(s, 2, 16);
                    s += __shfl_xor(s, 4, 16);
                    s += __shfl_xor(s, 8, 16);
                    if (l16 == 0) {
                        const int gm = gm0 + r;
                        knG[(size_t)(b * 16 + hh) * 2048 + (gm & 2047)] = s;
                    }
                }
            }
        }
    } else {
        // -------- 1-term path (V) --------
        for (int k0 = 0; k0 < 1024; k0 += 32) {
            gload16(gAh + k0, lAh);
            gload16(gAh + 64 * 1024 + k0, lAh + 64 * 32);
            gload16(gBh + k0, lBh);
            gload16(gBh + 64 * 1024 + k0, lBh + 64 * 32);
            __syncthreads();
            bf16x8 af[4], bf_[4];
#pragma unroll
            for (int i = 0; i < 4; i++)
                af[i] = *(bf16x8*)&Ash[(wm + i * 16 + l16) * 32 + quad * 8];
#pragma unroll
            for (int j = 0; j < 4; j++)
                bf_[j] = *(bf16x8*)&Bsh[(wn + j * 16 + l16) * 32 + quad * 8];
#pragma unroll
            for (int i = 0; i < 4; i++)
#pragma unroll
                for (int j = 0; j < 4; j++)
                    acc[i][j] = MFMA16(af[i], bf_[j], acc[i][j]);
            __syncthreads();
        }

#pragma unroll
        for (int i = 0; i < 4; i++)
#pragma unroll
            for (int j = 0; j < 4; j++) {
                const int o = (n0 + wn + j * 16 + l16) & 1023;
                const int h = o >> 6, d = o & 63;
                const float bvv = bv[o];
                const int gm0 = m0 + wm + i * 16 + quad * 4;
                const int b = gm0 >> 11;
                bf16x4 pv;
#pragma unroll
                for (int r = 0; r < 4; r++) pv[r] = (bf16)(acc[i][j][r] + bvv);
                const int s0 = gm0 & 2047;
                *(bf16x4*)&VtG[((size_t)((b * 16 + h) * 64 + d)) * 2048 + s0] = pv;
            }
    }
}

// ---------------------------------------------------------------------------
// K2: flash attention, YAT scores, 32x32x16 MFMA, in-register P via
//   cvt_pk_bf16 + permlane32_swap, XOR-swizzled stride-64 reg staging
//   (async-split), double-buffered, constant-shift softmax. (R1-proven)
//   Per wave: 32 q rows. Lane layout: q = lane&31, h = lane>>5.
// ---------------------------------------------------------------------------
__global__ __launch_bounds__(256, 2) void attn_kernel(
    const bf16* __restrict__ Qh, const bf16* __restrict__ Ql,
    const bf16* __restrict__ Kh, const bf16* __restrict__ Kl,
    const bf16* __restrict__ VtG, const float* __restrict__ knG,
    bf16* __restrict__ O, const float* __restrict__ alphap) {
    __shared__ bf16 Ksh[2][64 * 64];
    __shared__ bf16 Ksl[2][64 * 64];
    __shared__ bf16 Vs[2][64 * 64];
    __shared__ __align__(16) float knL[2][64];

    const int t = threadIdx.x, lane = t & 63, wave = t >> 6;
    const int l31 = lane & 31, h = lane >> 5;
    const int bh = blockIdx.x;
    const int qw = blockIdx.y * 128 + wave * 32;

    const float alpha = alphap[0];
    const float C = powf(8.0f / log1pf(64.0f), alpha) * 1.44269504f;

    // Q fragments (B-operand): lane holds Q[q=l31][d = cb*16 + h*8 + j]
    const size_t qbase = ((size_t)bh * 2048 + qw + l31) * 64;
    bf16x8 bqh[4], bql[4];
#pragma unroll
    for (int cb = 0; cb < 4; cb++) {
        bqh[cb] = *(const bf16x8*)(Qh + qbase + cb * 16 + h * 8);
        bql[cb] = *(const bf16x8*)(Ql + qbase + cb * 16 + h * 8);
    }
    float qn = 0.f;
#pragma unroll
    for (int cb = 0; cb < 4; cb++)
#pragma unroll
        for (int j = 0; j < 8; j++) {
            float x = (float)bqh[cb][j] + (float)bql[cb][j];
            qn += x * x;
        }
    qn += __shfl_xor(qn, 32, 64);
    const float qne = qn + 1e-5f;

    floatx16 acco[2] = {};
    float l_run = 0.f;

    // staging map: thread t stages rows srow, srow+32; 8 elems at scol
    const int srow = t >> 3;
    const int scol = (t & 7) * 8;
    const int smask = (srow & 7) * 8;  // (srow+32)&7 == srow&7
    const int so0 = srow * 64 + (scol ^ smask);
    const int so1 = (srow + 32) * 64 + (scol ^ smask);
    const size_t vrow0 = ((size_t)bh * 64 + srow) * 2048;
    const size_t vrow1 = vrow0 + (size_t)32 * 2048;
    const float* knB = knG + (size_t)bh * 2048;

    // fragment read offsets: row-block rb (32 rows) x col-block cb (16 elems)
    const int fmask = (l31 & 7) * 8;
    int foff[2][4];
#pragma unroll
    for (int rb = 0; rb < 2; rb++)
#pragma unroll
        for (int cb = 0; cb < 4; cb++)
            foff[rb][cb] = (rb * 32 + l31) * 64 + ((cb * 16 + h * 8) ^ fmask);

    auto do_chunk = [&](int ib) {
        const bf16* KH = Ksh[ib];
        const bf16* KL = Ksl[ib];
        const bf16* VV = Vs[ib];
        const float* knC = knL[ib];

        // QK^T (swapped): D[key][q], 3-term split
        floatx16 acc[2] = {};
#pragma unroll
        for (int cb = 0; cb < 4; cb++)
#pragma unroll
            for (int kb = 0; kb < 2; kb++) {
                bf16x8 ah = *(const bf16x8*)&KH[foff[kb][cb]];
                bf16x8 al = *(const bf16x8*)&KL[foff[kb][cb]];
                acc[kb] = MFMA32(ah, bqh[cb], acc[kb]);
                acc[kb] = MFMA32(ah, bql[cb], acc[kb]);
                acc[kb] = MFMA32(al, bqh[cb], acc[kb]);
            }

        // softmax (constant shift) + pack P into PV B-operand fragments.
        // lane's key for acc[kb][r]: kb*32 + (r&3) + 8*(r>>2) + 4*h
        unsigned pw[2][8];
        float rs = 0.f;
#pragma unroll
        for (int kb = 0; kb < 2; kb++) {
            float p[16];
#pragma unroll
            for (int g2 = 0; g2 < 4; g2++) {
                const floatx4 knv = *(const floatx4*)&knC[kb * 32 + g2 * 8 + h * 4];
#pragma unroll
                for (int j = 0; j < 4; j++) {
                    const int r = g2 * 4 + j;
                    const float d = acc[kb][r];
                    const float e = fmaf(-2.0f, d, qne + knv[j]);
                    const float s = fmaf(C * d * d, __builtin_amdgcn_rcpf(e), -110.0f);
                    const float pp = __builtin_amdgcn_exp2f(s);
                    rs += pp;
                    p[r] = pp;
                }
            }
#pragma unroll
            for (int g = 0; g < 2; g++) {
                unsigned a0 = cvt_pk(p[8 * g + 0], p[8 * g + 1]);
                unsigned a1 = cvt_pk(p[8 * g + 2], p[8 * g + 3]);
                unsigned b0 = cvt_pk(p[8 * g + 4], p[8 * g + 5]);
                unsigned b1 = cvt_pk(p[8 * g + 6], p[8 * g + 7]);
                pl32swap(a0, b0);
                pl32swap(a1, b1);
                pw[kb][g * 4 + 0] = a0;
                pw[kb][g * 4 + 1] = a1;
                pw[kb][g * 4 + 2] = b0;
                pw[kb][g * 4 + 3] = b1;
            }
        }
        l_run += rs;

        // PV: D[d][q] += V[d][key] * P[key][q]
#pragma unroll
        for (int db = 0; db < 2; db++)
#pragma unroll
            for (int g4 = 0; g4 < 4; g4++) {
                bf16x8 vf = *(const bf16x8*)&VV[foff[db][g4]];
                union { unsigned u[4]; bf16x8 v; } pu;
                pu.u[0] = pw[g4 >> 1][(g4 & 1) * 4 + 0];
                pu.u[1] = pw[g4 >> 1][(g4 & 1) * 4 + 1];
                pu.u[2] = pw[g4 >> 1][(g4 & 1) * 4 + 2];
                pu.u[3] = pw[g4 >> 1][(g4 & 1) * 4 + 3];
                acco[db] = MFMA32(vf, pu.v, acco[db]);
            }
    };

    {
        const size_t kb0 = (size_t)(bh * 2048) * 64;
        bf16x8 k0 = *(const bf16x8*)(Kh + kb0 + srow * 64 + scol);
        bf16x8 k1 = *(const bf16x8*)(Kh + kb0 + (32 + srow) * 64 + scol);
        bf16x8 c0 = *(const bf16x8*)(Kl + kb0 + srow * 64 + scol);
        bf16x8 c1 = *(const bf16x8*)(Kl + kb0 + (32 + srow) * 64 + scol);
        bf16x8 v0 = *(const bf16x8*)(VtG + vrow0 + scol);
        bf16x8 v1 = *(const bf16x8*)(VtG + vrow1 + scol);
        *(bf16x8*)&Ksh[0][so0] = k0;
        *(bf16x8*)&Ksh[0][so1] = k1;
        *(bf16x8*)&Ksl[0][so0] = c0;
        *(bf16x8*)&Ksl[0][so1] = c1;
        *(bf16x8*)&Vs[0][so0] = v0;
        *(bf16x8*)&Vs[0][so1] = v1;
        if (t < 16) *(float4*)&knL[0][t * 4] = *(const float4*)(knB + t * 4);
    }
    __syncthreads();

    for (int ic = 0; ic < 31; ic++) {
        const int cur = ic & 1, nxt = cur ^ 1;
        const int kc = (ic + 1) * 64;
        const size_t kbg = (size_t)(bh * 2048 + kc) * 64;
        bf16x8 nk0 = *(const bf16x8*)(Kh + kbg + srow * 64 + scol);
        bf16x8 nk1 = *(const bf16x8*)(Kh + kbg + (32 + srow) * 64 + scol);
        bf16x8 nc0 = *(const bf16x8*)(Kl + kbg + srow * 64 + scol);
        bf16x8 nc1 = *(const bf16x8*)(Kl + kbg + (32 + srow) * 64 + scol);
        bf16x8 nv0 = *(const bf16x8*)(VtG + vrow0 + kc + scol);
        bf16x8 nv1 = *(const bf16x8*)(VtG + vrow1 + kc + scol);
        float4 nkn;
        if (t < 16) nkn = *(const float4*)(knB + kc + t * 4);

        do_chunk(cur);

        *(bf16x8*)&Ksh[nxt][so0] = nk0;
        *(bf16x8*)&Ksh[nxt][so1] = nk1;
        *(bf16x8*)&Ksl[nxt][so0] = nc0;
        *(bf16x8*)&Ksl[nxt][so1] = nc1;
        *(bf16x8*)&Vs[nxt][so0] = nv0;
        *(bf16x8*)&Vs[nxt][so1] = nv1;
        if (t < 16) *(float4*)&knL[nxt][t * 4] = nkn;
        __syncthreads();
    }
    do_chunk(1);

    const float l_tot = l_run + __shfl_xor(l_run, 32, 64);
    const float rl = 1.0f / l_tot;
    const int b = bh >> 4, hh = bh & 15;
    const int q = qw + l31;
    const size_t obase = (size_t)(b * 2048 + q) * 1024 + hh * 64;
#pragma unroll
    for (int db = 0; db < 2; db++)
#pragma unroll
        for (int g2 = 0; g2 < 4; g2++) {
            bf16x4 ov;
#pragma unroll
            for (int j = 0; j < 4; j++) ov[j] = (bf16)(acco[db][g2 * 4 + j] * rl);
            const int d = db * 32 + g2 * 8 + h * 4;
            *(bf16x4*)&O[obase + d] = ov;
        }
}

// ---------------------------------------------------------------------------
// K3: out-proj GEMM, 128x64 tile (512 blocks), fp32 out  (R7-proven)
// ---------------------------------------------------------------------------
__global__ __launch_bounds__(256, 2) void gemm_out(
    const bf16* __restrict__ A, const bf16* __restrict__ Bt,
    const float* __restrict__ bias, float* __restrict__ outC) {
    __shared__ bf16 As[128 * 32];
    __shared__ bf16 Bs[64 * 32];

    const int t = threadIdx.x;
    const int lane = t & 63, wave = t >> 6;
    const int quad = lane >> 4, l16 = lane & 15;
    const int m0 = blockIdx.x * 128, n0 = blockIdx.y * 64;
    const int wm = (wave >> 1) * 64, wn = (wave & 1) * 32;

    const int srow = wave * 16 + (lane >> 2);
    const int scol = (lane & 3) * 8;
    const bf16* gA0 = A + (size_t)(m0 + srow) * 1024 + scol;
    const bf16* gB0 = Bt + (size_t)(n0 + srow) * 1024 + scol;
    bf16* lA = &As[wave * 16 * 32];
    bf16* lB = &Bs[wave * 16 * 32];

    floatx4 acc[4][2] = {};

    for (int k0 = 0; k0 < 1024; k0 += 32) {
        gload16(gA0 + k0, lA);
        gload16(gA0 + 64 * 1024 + k0, lA + 64 * 32);
        gload16(gB0 + k0, lB);
        __syncthreads();
        bf16x8 af[4], bf_[2];
#pragma unroll
        for (int i = 0; i < 4; i++)
            af[i] = *(bf16x8*)&As[(wm + i * 16 + l16) * 32 + quad * 8];
#pragma unroll
        for (int j = 0; j < 2; j++)
            bf_[j] = *(bf16x8*)&Bs[(wn + j * 16 + l16) * 32 + quad * 8];
#pragma unroll
        for (int i = 0; i < 4; i++)
#pragma unroll
            for (int j = 0; j < 2; j++)
                acc[i][j] = MFMA16(af[i], bf_[j], acc[i][j]);
        __syncthreads();
    }

#pragma unroll
    for (int i = 0; i < 4; i++)
#pragma unroll
        for (int j = 0; j < 2; j++) {
            const int col = n0 + wn + j * 16 + l16;
            const float bvv = bias[col];
#pragma unroll
            for (int r = 0; r < 4; r++) {
                const int gm = m0 + wm + i * 16 + quad * 4 + r;
                outC[(size_t)gm * 1024 + col] = acc[i][j][r] + bvv;
            }
        }
}

// ---------------------------------------------------------------------------
extern "C" void kernel_launch(void* const* d_in, const int* in_sizes, int n_in,
                              void* d_out, int out_size, void* d_ws, size_t ws_size,
                              hipStream_t stream) {
    const float* x  = (const float*)d_in[0];
    const float* wq = (const float*)d_in[1];
    const float* bq = (const float*)d_in[2];
    const float* wk = (const float*)d_in[3];
    const float* bk = (const float*)d_in[4];
    const float* wv = (const float*)d_in[5];
    const float* bv = (const float*)d_in[6];
    const float* wo = (const float*)d_in[7];
    const float* bo = (const float*)d_in[8];
    const float* alpha = (const float*)d_in[9];

    char* ws = (char*)d_ws;
    const size_t MB = 1024 * 1024;
    bf16* wqkv_h = (bf16*)(ws);              // 6 MB
    bf16* wqkv_l = (bf16*)(ws + 6 * MB);     // 6 MB
    bf16* wo_h   = (bf16*)(ws + 12 * MB);    // 2 MB
    float* knG   = (float*)(ws + 14 * MB);   // 0.25 MB
    bf16* x_h    = (bf16*)(ws + 16 * MB);    // 8 MB
    bf16* x_l    = (bf16*)(ws + 24 * MB);    // 8 MB
    bf16* Q_h    = (bf16*)(ws + 32 * MB);    // 8 MB
    bf16* Q_l    = (bf16*)(ws + 40 * MB);    // 8 MB
    bf16* K_h    = (bf16*)(ws + 48 * MB);    // 8 MB
    bf16* K_l    = (bf16*)(ws + 56 * MB);    // 8 MB
    bf16* Vt_g   = (bf16*)(ws + 64 * MB);    // 8 MB, [B,H,D,S]
    bf16* Ob     = (bf16*)(ws);              // aliases wqkv (dead after QKV GEMM)

    prep_kernel<<<dim3(32, 32, 5), dim3(32, 8), 0, stream>>>(
        x, wq, wk, wv, wo, x_h, x_l, wqkv_h, wqkv_l, wo_h);
    gemm_qkv<<<dim3(32, 24), 256, 0, stream>>>(
        x_h, x_l, wqkv_h, wqkv_l, bq, bk, bv, Q_h, Q_l, K_h, K_l, Vt_g, knG);
    attn_kernel<<<dim3(32, 16), 256, 0, stream>>>(
        Q_h, Q_l, K_h, K_l, Vt_g, knG, Ob, alpha);
    gemm_out<<<dim3(32, 16), 256, 0, stream>>>(Ob, wo_h, bo, (float*)d_out);
}

// Round 11
// 259.886 us; speedup vs baseline: 1.1188x; 1.0164x over previous
//
#include <hip/hip_runtime.h>
#include <hip/hip_bf16.h>
#include <math.h>

typedef __bf16 bf16;
typedef bf16 bf16x4 __attribute__((ext_vector_type(4)));
typedef bf16 bf16x8 __attribute__((ext_vector_type(8)));
typedef float floatx4 __attribute__((ext_vector_type(4)));
typedef float floatx16 __attribute__((ext_vector_type(16)));

#define MFMA16(a, b, c) __builtin_amdgcn_mfma_f32_16x16x32_bf16(a, b, c, 0, 0, 0)
#define MFMA32(a, b, c) __builtin_amdgcn_mfma_f32_32x32x16_bf16(a, b, c, 0, 0, 0)

__device__ __forceinline__ void split2(float v, bf16& h, bf16& l) {
    h = (bf16)v;
    l = (bf16)(v - (float)h);
}

// pack two f32 -> one u32 of 2 bf16 (lo in [15:0], hi in [31:16])
__device__ __forceinline__ unsigned cvt_pk(float lo, float hi) {
    unsigned r;
    asm("v_cvt_pk_bf16_f32 %0, %1, %2" : "=v"(r) : "v"(lo), "v"(hi));
    return r;
}

// swap a.hi_lanes <-> b.lo_lanes
__device__ __forceinline__ void pl32swap(unsigned& a, unsigned& b) {
    asm("v_permlane32_swap_b32 %0, %1" : "+v"(a), "+v"(b));
}

// async global->LDS, 16 B per lane; LDS dest = wave-uniform base + lane*16
__device__ __forceinline__ void gload16(const bf16* g, bf16* l) {
    __builtin_amdgcn_global_load_lds(
        (const __attribute__((address_space(1))) void*)g,
        (__attribute__((address_space(3))) void*)l, 16, 0, 0);
}

// ---------------------------------------------------------------------------
// K0: z<4: transpose+split fp32 weights W[k][n] -> hi/lo bf16 Wt[n][k]
//     (bf16x8 stores, coalescing-correct lane map); z==4: split x (flat)
// ---------------------------------------------------------------------------
__global__ void prep_kernel(const float* __restrict__ xf,
                            const float* __restrict__ wq, const float* __restrict__ wk,
                            const float* __restrict__ wv, const float* __restrict__ wo,
                            bf16* __restrict__ xh, bf16* __restrict__ xl,
                            bf16* __restrict__ wt_qkv_h, bf16* __restrict__ wt_qkv_l,
                            bf16* __restrict__ wt_o_h) {
    const int z = blockIdx.z;
    if (z == 4) {
        const int tid = threadIdx.y * 32 + threadIdx.x;
        const int bid = blockIdx.y * 32 + blockIdx.x;
        const size_t i = ((size_t)bid * 256 + tid) * 16;
#pragma unroll
        for (int half = 0; half < 2; half++) {
            float4 a = *(const float4*)(xf + i + half * 8);
            float4 b = *(const float4*)(xf + i + half * 8 + 4);
            bf16x8 oh, ol;
            float f[8] = {a.x, a.y, a.z, a.w, b.x, b.y, b.z, b.w};
#pragma unroll
            for (int j = 0; j < 8; j++) { bf16 h, l; split2(f[j], h, l); oh[j] = h; ol[j] = l; }
            *(bf16x8*)(xh + i + half * 8) = oh;
            *(bf16x8*)(xl + i + half * 8) = ol;
        }
        return;
    }
    const float* src = (z == 0) ? wq : (z == 1) ? wk : (z == 2) ? wv : wo;
    bf16* dsth = (z < 3) ? (wt_qkv_h + (size_t)z * 1024 * 1024) : wt_o_h;
    bf16* dstl = (z < 3) ? (wt_qkv_l + (size_t)z * 1024 * 1024) : nullptr;
    __shared__ float tile[32][33];
    const int x0 = blockIdx.x * 32, y0 = blockIdx.y * 32;
    const int tx = threadIdx.x, ty = threadIdx.y;  // (32,8)
    for (int i = 0; i < 32; i += 8)
        tile[ty + i][tx] = src[(size_t)(y0 + ty + i) * 1024 + x0 + tx];
    __syncthreads();
    // vectorized transpose-out: Wt[n=x0+r][k=y0+c0*8+j] = tile[c0*8+j][r].
    const int id = ty * 32 + tx;
    const int r = id >> 3, hf = (id >> 2) & 1, c0 = id & 3;
    bf16x8 v;
#pragma unroll
    for (int j = 0; j < 8; j++) {
        bf16 h, l;
        split2(tile[c0 * 8 + j][r], h, l);
        v[j] = hf ? l : h;
    }
    bf16* dst = hf ? dstl : dsth;
    if (dst) *(bf16x8*)&dst[(size_t)(x0 + r) * 1024 + y0 + c0 * 8] = v;
}

// ---------------------------------------------------------------------------
// K1: FUSED QKV GEMM over N=3072 (Q,K: 3-term split-bf16; V: 1-term),
//   grid 32x24 = 768 blocks = 3 blocks/CU (launch_bounds(256,3)).
//   PANEL-SWIZZLED tile map (bijective, balance-preserving): XCD k (id%8)
//   processes y in {k, k+8, k+16} -> its 3 B-panels (one Q, one K, one V,
//   1.25 MB total) stay L2-resident; per-CU Q/K/V work mix preserved.
//   Q/K epilogue writes hi/lo [B,H,S,D]; K blocks also reduce
//   kn = sum_d (hi+lo)^2 in-register. V epilogue writes Vt[B,H,D,S].
// ---------------------------------------------------------------------------
__global__ __launch_bounds__(256, 3) void gemm_qkv(
    const bf16* __restrict__ Ah, const bf16* __restrict__ Al,
    const bf16* __restrict__ Bth, const bf16* __restrict__ Btl,
    const float* __restrict__ bq, const float* __restrict__ bk,
    const float* __restrict__ bv,
    bf16* __restrict__ Qh, bf16* __restrict__ Ql,
    bf16* __restrict__ Kh, bf16* __restrict__ Kl,
    bf16* __restrict__ VtG, float* __restrict__ knG) {
    __shared__ bf16 Ash[128 * 32];
    __shared__ bf16 Asl[128 * 32];
    __shared__ bf16 Bsh[128 * 32];
    __shared__ bf16 Bsl[128 * 32];

    const int t = threadIdx.x;
    const int lane = t & 63, wave = t >> 6;
    const int quad = lane >> 4, l16 = lane & 15;
    // panel swizzle: id%8 selects XCD; give it y = k, k+8, k+16
    const int id = blockIdx.y * 32 + blockIdx.x;
    const int jj = id >> 3;
    const int by = (id & 7) + 8 * (jj >> 5);
    const int bx = jj & 31;
    const int m0 = bx * 128, n0 = by * 128;
    const int wm = (wave >> 1) * 64, wn = (wave & 1) * 64;
    const int which = n0 >> 10;  // 0=Q 1=K 2=V

    const int srow = wave * 16 + (lane >> 2);
    const int scol = (lane & 3) * 8;
    const bf16* gAh = Ah + (size_t)(m0 + srow) * 1024 + scol;
    const bf16* gAl = Al + (size_t)(m0 + srow) * 1024 + scol;
    const bf16* gBh = Bth + (size_t)(n0 + srow) * 1024 + scol;
    const bf16* gBl = Btl + (size_t)(n0 + srow) * 1024 + scol;
    bf16* lAh = &Ash[wave * 16 * 32];
    bf16* lAl = &Asl[wave * 16 * 32];
    bf16* lBh = &Bsh[wave * 16 * 32];
    bf16* lBl = &Bsl[wave * 16 * 32];

    floatx4 acc[4][4] = {};

    if (which < 2) {
        // -------- 3-term split path (Q and K) --------
        for (int k0 = 0; k0 < 1024; k0 += 32) {
            gload16(gAh + k0, lAh);
            gload16(gAh + 64 * 1024 + k0, lAh + 64 * 32);
            gload16(gBh + k0, lBh);
            gload16(gBh + 64 * 1024 + k0, lBh + 64 * 32);
            gload16(gAl + k0, lAl);
            gload16(gAl + 64 * 1024 + k0, lAl + 64 * 32);
            gload16(gBl + k0, lBl);
            gload16(gBl + 64 * 1024 + k0, lBl + 64 * 32);
            __syncthreads();
            bf16x8 afh[4], bfh[4], afl[4], bfl[4];
#pragma unroll
            for (int i = 0; i < 4; i++) {
                afh[i] = *(bf16x8*)&Ash[(wm + i * 16 + l16) * 32 + quad * 8];
                afl[i] = *(bf16x8*)&Asl[(wm + i * 16 + l16) * 32 + quad * 8];
            }
#pragma unroll
            for (int j = 0; j < 4; j++) {
                bfh[j] = *(bf16x8*)&Bsh[(wn + j * 16 + l16) * 32 + quad * 8];
                bfl[j] = *(bf16x8*)&Bsl[(wn + j * 16 + l16) * 32 + quad * 8];
            }
#pragma unroll
            for (int i = 0; i < 4; i++)
#pragma unroll
                for (int j = 0; j < 4; j++) {
                    acc[i][j] = MFMA16(afh[i], bfh[j], acc[i][j]);
                    acc[i][j] = MFMA16(afh[i], bfl[j], acc[i][j]);
                    acc[i][j] = MFMA16(afl[i], bfh[j], acc[i][j]);
                }
            __syncthreads();
        }

        const float* bias = (which == 0) ? bq : bk;
        bf16* Dh = (which == 0) ? Qh : Kh;
        bf16* Dl = (which == 0) ? Ql : Kl;
        const int hh = ((n0 + wn) & 1023) >> 6;  // head of this wave's 64 cols
#pragma unroll
        for (int i = 0; i < 4; i++) {
            float ks[4] = {0.f, 0.f, 0.f, 0.f};
#pragma unroll
            for (int j = 0; j < 4; j++) {
                const int col = n0 + wn + j * 16 + l16;
                const int o = col & 1023;
                const int h = o >> 6, d = o & 63;
                const float bvv = bias[o];
                const int gm0 = m0 + wm + i * 16 + quad * 4;
                const int b = gm0 >> 11;
#pragma unroll
                for (int r = 0; r < 4; r++) {
                    const int gm = gm0 + r;
                    const int s = gm & 2047;
                    const size_t idx = (size_t)((b * 16 + h) * 2048 + s) * 64 + d;
                    const float val = acc[i][j][r] + bvv;
                    bf16 hi, lo;
                    split2(val, hi, lo);
                    Dh[idx] = hi;
                    Dl[idx] = lo;
                    const float vr = (float)hi + (float)lo;
                    ks[r] += vr * vr;
                }
            }
            if (which == 1) {
                const int gm0 = m0 + wm + i * 16 + quad * 4;
                const int b = gm0 >> 11;
#pragma unroll
                for (int r = 0; r < 4; r++) {
                    float s = ks[r];
                    s += __shfl_xor(s, 1, 16);
                    s += __shfl_xor(s, 2, 16);
                    s += __shfl_xor(s, 4, 16);
                    s += __shfl_xor(s, 8, 16);
                    if (l16 == 0) {
                        const int gm = gm0 + r;
                        knG[(size_t)(b * 16 + hh) * 2048 + (gm & 2047)] = s;
                    }
                }
            }
        }
    } else {
        // -------- 1-term path (V) --------
        for (int k0 = 0; k0 < 1024; k0 += 32) {
            gload16(gAh + k0, lAh);
            gload16(gAh + 64 * 1024 + k0, lAh + 64 * 32);
            gload16(gBh + k0, lBh);
            gload16(gBh + 64 * 1024 + k0, lBh + 64 * 32);
            __syncthreads();
            bf16x8 af[4], bf_[4];
#pragma unroll
            for (int i = 0; i < 4; i++)
                af[i] = *(bf16x8*)&Ash[(wm + i * 16 + l16) * 32 + quad * 8];
#pragma unroll
            for (int j = 0; j < 4; j++)
                bf_[j] = *(bf16x8*)&Bsh[(wn + j * 16 + l16) * 32 + quad * 8];
#pragma unroll
            for (int i = 0; i < 4; i++)
#pragma unroll
                for (int j = 0; j < 4; j++)
                    acc[i][j] = MFMA16(af[i], bf_[j], acc[i][j]);
            __syncthreads();
        }

#pragma unroll
        for (int i = 0; i < 4; i++)
#pragma unroll
            for (int j = 0; j < 4; j++) {
                const int o = (n0 + wn + j * 16 + l16) & 1023;
                const int h = o >> 6, d = o & 63;
                const float bvv = bv[o];
                const int gm0 = m0 + wm + i * 16 + quad * 4;
                const int b = gm0 >> 11;
                bf16x4 pv;
#pragma unroll
                for (int r = 0; r < 4; r++) pv[r] = (bf16)(acc[i][j][r] + bvv);
                const int s0 = gm0 & 2047;
                *(bf16x4*)&VtG[((size_t)((b * 16 + h) * 64 + d)) * 2048 + s0] = pv;
            }
    }
}

// ---------------------------------------------------------------------------
// K2: flash attention, YAT scores, 32x32x16 MFMA, in-register P via
//   cvt_pk_bf16 + permlane32_swap, XOR-swizzled stride-64 reg staging
//   (async-split), double-buffered, constant-shift softmax. (R1-proven)
//   Natural bh->XCD locality (stride-32 ids): untouched.
// ---------------------------------------------------------------------------
__global__ __launch_bounds__(256, 2) void attn_kernel(
    const bf16* __restrict__ Qh, const bf16* __restrict__ Ql,
    const bf16* __restrict__ Kh, const bf16* __restrict__ Kl,
    const bf16* __restrict__ VtG, const float* __restrict__ knG,
    bf16* __restrict__ O, const float* __restrict__ alphap) {
    __shared__ bf16 Ksh[2][64 * 64];
    __shared__ bf16 Ksl[2][64 * 64];
    __shared__ bf16 Vs[2][64 * 64];
    __shared__ __align__(16) float knL[2][64];

    const int t = threadIdx.x, lane = t & 63, wave = t >> 6;
    const int l31 = lane & 31, h = lane >> 5;
    const int bh = blockIdx.x;
    const int qw = blockIdx.y * 128 + wave * 32;

    const float alpha = alphap[0];
    const float C = powf(8.0f / log1pf(64.0f), alpha) * 1.44269504f;

    // Q fragments (B-operand): lane holds Q[q=l31][d = cb*16 + h*8 + j]
    const size_t qbase = ((size_t)bh * 2048 + qw + l31) * 64;
    bf16x8 bqh[4], bql[4];
#pragma unroll
    for (int cb = 0; cb < 4; cb++) {
        bqh[cb] = *(const bf16x8*)(Qh + qbase + cb * 16 + h * 8);
        bql[cb] = *(const bf16x8*)(Ql + qbase + cb * 16 + h * 8);
    }
    float qn = 0.f;
#pragma unroll
    for (int cb = 0; cb < 4; cb++)
#pragma unroll
        for (int j = 0; j < 8; j++) {
            float x = (float)bqh[cb][j] + (float)bql[cb][j];
            qn += x * x;
        }
    qn += __shfl_xor(qn, 32, 64);
    const float qne = qn + 1e-5f;

    floatx16 acco[2] = {};
    float l_run = 0.f;

    // staging map: thread t stages rows srow, srow+32; 8 elems at scol
    const int srow = t >> 3;
    const int scol = (t & 7) * 8;
    const int smask = (srow & 7) * 8;  // (srow+32)&7 == srow&7
    const int so0 = srow * 64 + (scol ^ smask);
    const int so1 = (srow + 32) * 64 + (scol ^ smask);
    const size_t vrow0 = ((size_t)bh * 64 + srow) * 2048;
    const size_t vrow1 = vrow0 + (size_t)32 * 2048;
    const float* knB = knG + (size_t)bh * 2048;

    // fragment read offsets: row-block rb (32 rows) x col-block cb (16 elems)
    const int fmask = (l31 & 7) * 8;
    int foff[2][4];
#pragma unroll
    for (int rb = 0; rb < 2; rb++)
#pragma unroll
        for (int cb = 0; cb < 4; cb++)
            foff[rb][cb] = (rb * 32 + l31) * 64 + ((cb * 16 + h * 8) ^ fmask);

    auto do_chunk = [&](int ib) {
        const bf16* KH = Ksh[ib];
        const bf16* KL = Ksl[ib];
        const bf16* VV = Vs[ib];
        const float* knC = knL[ib];

        // QK^T (swapped): D[key][q], 3-term split
        floatx16 acc[2] = {};
#pragma unroll
        for (int cb = 0; cb < 4; cb++)
#pragma unroll
            for (int kb = 0; kb < 2; kb++) {
                bf16x8 ah = *(const bf16x8*)&KH[foff[kb][cb]];
                bf16x8 al = *(const bf16x8*)&KL[foff[kb][cb]];
                acc[kb] = MFMA32(ah, bqh[cb], acc[kb]);
                acc[kb] = MFMA32(ah, bql[cb], acc[kb]);
                acc[kb] = MFMA32(al, bqh[cb], acc[kb]);
            }

        // softmax (constant shift) + pack P into PV B-operand fragments.
        // lane's key for acc[kb][r]: kb*32 + (r&3) + 8*(r>>2) + 4*h
        unsigned pw[2][8];
        float rs = 0.f;
#pragma unroll
        for (int kb = 0; kb < 2; kb++) {
            float p[16];
#pragma unroll
            for (int g2 = 0; g2 < 4; g2++) {
                const floatx4 knv = *(const floatx4*)&knC[kb * 32 + g2 * 8 + h * 4];
#pragma unroll
                for (int j = 0; j < 4; j++) {
                    const int r = g2 * 4 + j;
                    const float d = acc[kb][r];
                    const float e = fmaf(-2.0f, d, qne + knv[j]);
                    const float s = fmaf(C * d * d, __builtin_amdgcn_rcpf(e), -110.0f);
                    const float pp = __builtin_amdgcn_exp2f(s);
                    rs += pp;
                    p[r] = pp;
                }
            }
#pragma unroll
            for (int g = 0; g < 2; g++) {
                unsigned a0 = cvt_pk(p[8 * g + 0], p[8 * g + 1]);
                unsigned a1 = cvt_pk(p[8 * g + 2], p[8 * g + 3]);
                unsigned b0 = cvt_pk(p[8 * g + 4], p[8 * g + 5]);
                unsigned b1 = cvt_pk(p[8 * g + 6], p[8 * g + 7]);
                pl32swap(a0, b0);
                pl32swap(a1, b1);
                pw[kb][g * 4 + 0] = a0;
                pw[kb][g * 4 + 1] = a1;
                pw[kb][g * 4 + 2] = b0;
                pw[kb][g * 4 + 3] = b1;
            }
        }
        l_run += rs;

        // PV: D[d][q] += V[d][key] * P[key][q]
#pragma unroll
        for (int db = 0; db < 2; db++)
#pragma unroll
            for (int g4 = 0; g4 < 4; g4++) {
                bf16x8 vf = *(const bf16x8*)&VV[foff[db][g4]];
                union { unsigned u[4]; bf16x8 v; } pu;
                pu.u[0] = pw[g4 >> 1][(g4 & 1) * 4 + 0];
                pu.u[1] = pw[g4 >> 1][(g4 & 1) * 4 + 1];
                pu.u[2] = pw[g4 >> 1][(g4 & 1) * 4 + 2];
                pu.u[3] = pw[g4 >> 1][(g4 & 1) * 4 + 3];
                acco[db] = MFMA32(vf, pu.v, acco[db]);
            }
    };

    {
        const size_t kb0 = (size_t)(bh * 2048) * 64;
        bf16x8 k0 = *(const bf16x8*)(Kh + kb0 + srow * 64 + scol);
        bf16x8 k1 = *(const bf16x8*)(Kh + kb0 + (32 + srow) * 64 + scol);
        bf16x8 c0 = *(const bf16x8*)(Kl + kb0 + srow * 64 + scol);
        bf16x8 c1 = *(const bf16x8*)(Kl + kb0 + (32 + srow) * 64 + scol);
        bf16x8 v0 = *(const bf16x8*)(VtG + vrow0 + scol);
        bf16x8 v1 = *(const bf16x8*)(VtG + vrow1 + scol);
        *(bf16x8*)&Ksh[0][so0] = k0;
        *(bf16x8*)&Ksh[0][so1] = k1;
        *(bf16x8*)&Ksl[0][so0] = c0;
        *(bf16x8*)&Ksl[0][so1] = c1;
        *(bf16x8*)&Vs[0][so0] = v0;
        *(bf16x8*)&Vs[0][so1] = v1;
        if (t < 16) *(float4*)&knL[0][t * 4] = *(const float4*)(knB + t * 4);
    }
    __syncthreads();

    for (int ic = 0; ic < 31; ic++) {
        const int cur = ic & 1, nxt = cur ^ 1;
        const int kc = (ic + 1) * 64;
        const size_t kbg = (size_t)(bh * 2048 + kc) * 64;
        bf16x8 nk0 = *(const bf16x8*)(Kh + kbg + srow * 64 + scol);
        bf16x8 nk1 = *(const bf16x8*)(Kh + kbg + (32 + srow) * 64 + scol);
        bf16x8 nc0 = *(const bf16x8*)(Kl + kbg + srow * 64 + scol);
        bf16x8 nc1 = *(const bf16x8*)(Kl + kbg + (32 + srow) * 64 + scol);
        bf16x8 nv0 = *(const bf16x8*)(VtG + vrow0 + kc + scol);
        bf16x8 nv1 = *(const bf16x8*)(VtG + vrow1 + kc + scol);
        float4 nkn;
        if (t < 16) nkn = *(const float4*)(knB + kc + t * 4);

        do_chunk(cur);

        *(bf16x8*)&Ksh[nxt][so0] = nk0;
        *(bf16x8*)&Ksh[nxt][so1] = nk1;
        *(bf16x8*)&Ksl[nxt][so0] = nc0;
        *(bf16x8*)&Ksl[nxt][so1] = nc1;
        *(bf16x8*)&Vs[nxt][so0] = nv0;
        *(bf16x8*)&Vs[nxt][so1] = nv1;
        if (t < 16) *(float4*)&knL[nxt][t * 4] = nkn;
        __syncthreads();
    }
    do_chunk(1);

    const float l_tot = l_run + __shfl_xor(l_run, 32, 64);
    const float rl = 1.0f / l_tot;
    const int b = bh >> 4, hh = bh & 15;
    const int q = qw + l31;
    const size_t obase = (size_t)(b * 2048 + q) * 1024 + hh * 64;
#pragma unroll
    for (int db = 0; db < 2; db++)
#pragma unroll
        for (int g2 = 0; g2 < 4; g2++) {
            bf16x4 ov;
#pragma unroll
            for (int j = 0; j < 4; j++) ov[j] = (bf16)(acco[db][g2 * 4 + j] * rl);
            const int d = db * 32 + g2 * 8 + h * 4;
            *(bf16x4*)&O[obase + d] = ov;
        }
}

// ---------------------------------------------------------------------------
// K3: out-proj GEMM, 128x64 tile (512 blocks), fp32 out, panel-swizzled
//   (XCD k gets y in {k, k+8}: its 2 B-panels stay L2-resident)
// ---------------------------------------------------------------------------
__global__ __launch_bounds__(256, 2) void gemm_out(
    const bf16* __restrict__ A, const bf16* __restrict__ Bt,
    const float* __restrict__ bias, float* __restrict__ outC) {
    __shared__ bf16 As[128 * 32];
    __shared__ bf16 Bs[64 * 32];

    const int t = threadIdx.x;
    const int lane = t & 63, wave = t >> 6;
    const int quad = lane >> 4, l16 = lane & 15;
    const int id = blockIdx.y * 32 + blockIdx.x;
    const int jj = id >> 3;
    const int by = (id & 7) + 8 * (jj >> 5);
    const int bx = jj & 31;
    const int m0 = bx * 128, n0 = by * 64;
    const int wm = (wave >> 1) * 64, wn = (wave & 1) * 32;

    const int srow = wave * 16 + (lane >> 2);
    const int scol = (lane & 3) * 8;
    const bf16* gA0 = A + (size_t)(m0 + srow) * 1024 + scol;
    const bf16* gB0 = Bt + (size_t)(n0 + srow) * 1024 + scol;
    bf16* lA = &As[wave * 16 * 32];
    bf16* lB = &Bs[wave * 16 * 32];

    floatx4 acc[4][2] = {};

    for (int k0 = 0; k0 < 1024; k0 += 32) {
        gload16(gA0 + k0, lA);
        gload16(gA0 + 64 * 1024 + k0, lA + 64 * 32);
        gload16(gB0 + k0, lB);
        __syncthreads();
        bf16x8 af[4], bf_[2];
#pragma unroll
        for (int i = 0; i < 4; i++)
            af[i] = *(bf16x8*)&As[(wm + i * 16 + l16) * 32 + quad * 8];
#pragma unroll
        for (int j = 0; j < 2; j++)
            bf_[j] = *(bf16x8*)&Bs[(wn + j * 16 + l16) * 32 + quad * 8];
#pragma unroll
        for (int i = 0; i < 4; i++)
#pragma unroll
            for (int j = 0; j < 2; j++)
                acc[i][j] = MFMA16(af[i], bf_[j], acc[i][j]);
        __syncthreads();
    }

#pragma unroll
    for (int i = 0; i < 4; i++)
#pragma unroll
        for (int j = 0; j < 2; j++) {
            const int col = n0 + wn + j * 16 + l16;
            const float bvv = bias[col];
#pragma unroll
            for (int r = 0; r < 4; r++) {
                const int gm = m0 + wm + i * 16 + quad * 4 + r;
                outC[(size_t)gm * 1024 + col] = acc[i][j][r] + bvv;
            }
        }
}

// ---------------------------------------------------------------------------
extern "C" void kernel_launch(void* const* d_in, const int* in_sizes, int n_in,
                              void* d_out, int out_size, void* d_ws, size_t ws_size,
                              hipStream_t stream) {
    const float* x  = (const float*)d_in[0];
    const float* wq = (const float*)d_in[1];
    const float* bq = (const float*)d_in[2];
    const float* wk = (const float*)d_in[3];
    const float* bk = (const float*)d_in[4];
    const float* wv = (const float*)d_in[5];
    const float* bv = (const float*)d_in[6];
    const float* wo = (const float*)d_in[7];
    const float* bo = (const float*)d_in[8];
    const float* alpha = (const float*)d_in[9];

    char* ws = (char*)d_ws;
    const size_t MB = 1024 * 1024;
    bf16* wqkv_h = (bf16*)(ws);              // 6 MB
    bf16* wqkv_l = (bf16*)(ws + 6 * MB);     // 6 MB
    bf16* wo_h   = (bf16*)(ws + 12 * MB);    // 2 MB
    float* knG   = (float*)(ws + 14 * MB);   // 0.25 MB
    bf16* x_h    = (bf16*)(ws + 16 * MB);    // 8 MB
    bf16* x_l    = (bf16*)(ws + 24 * MB);    // 8 MB
    bf16* Q_h    = (bf16*)(ws + 32 * MB);    // 8 MB
    bf16* Q_l    = (bf16*)(ws + 40 * MB);    // 8 MB
    bf16* K_h    = (bf16*)(ws + 48 * MB);    // 8 MB
    bf16* K_l    = (bf16*)(ws + 56 * MB);    // 8 MB
    bf16* Vt_g   = (bf16*)(ws + 64 * MB);    // 8 MB, [B,H,D,S]
    bf16* Ob     = (bf16*)(ws);              // aliases wqkv (dead after QKV GEMM)

    prep_kernel<<<dim3(32, 32, 5), dim3(32, 8), 0, stream>>>(
        x, wq, wk, wv, wo, x_h, x_l, wqkv_h, wqkv_l, wo_h);
    gemm_qkv<<<dim3(32, 24), 256, 0, stream>>>(
        x_h, x_l, wqkv_h, wqkv_l, bq, bk, bv, Q_h, Q_l, K_h, K_l, Vt_g, knG);
    attn_kernel<<<dim3(32, 16), 256, 0, stream>>>(
        Q_h, Q_l, K_h, K_l, Vt_g, knG, Ob, alpha);
    gemm_out<<<dim3(32, 16), 256, 0, stream>>>(Ob, wo_h, bo, (float*)d_out);
}